// Round 7
// baseline (59.796 us; speedup 1.0000x reference)
//
#include <hip/hip_runtime.h>
#include <hip/hip_bf16.h>
#include <math.h>

#define BS 8192
#define D 128
#define NROWS 16384               // 2*BS
#define BM 256                    // rows per block = 4 waves x 64
#define COLS_PER_BLOCK 512
#define NCHUNK (COLS_PER_BLOCK / 32)      // 16 col-chunks of 32
#define NSPLIT (NROWS / COLS_PER_BLOCK)   // 32
#define NPART NSPLIT                      // 32 partial buffers
#define KCSTR (NROWS * 16)                // 262144 B per kc-plane (16 cols... bytes)

typedef __bf16 bf16x8 __attribute__((ext_vector_type(8)));
typedef float f32x4 __attribute__((ext_vector_type(4)));

#define SQRT_LOG2E 1.2011224087864498f
#define LN2F 0.6931471805599453f

#if __has_builtin(__builtin_amdgcn_exp2f)
#define EXP2F(x) __builtin_amdgcn_exp2f(x)
#else
#define EXP2F(x) exp2f(x)
#endif

// Kernel 1: row norms + pre-scaled bf16 conversion into kc-major layout:
//   catT byte addr of (row, k) = (k>>3)*KCSTR + row*16 + (k&7)*2
// i.e. 16 planes of [16384 cols x 16B], so an MFMA fragment load (16 lanes x
// consecutive cols x 16B) is 4 contiguous 256B runs per wave-instruction.
// Rows scaled by sqrt(log2e)/||row|| so MFMA yields cos_sim*log2e directly.
__global__ __launch_bounds__(256) void nrm_cvt(const float* __restrict__ f,
                                               const float* __restrict__ noise,
                                               char* __restrict__ catT) {
  const int lane = threadIdx.x & 63;
  const int wv = threadIdx.x >> 6;
  const int row = blockIdx.x * 4 + wv;
  const float* src = (row < BS) ? (noise + (size_t)row * D) : (f + (size_t)(row - BS) * D);
  float2 v = ((const float2*)src)[lane];   // k = 2*lane, 2*lane+1
  float ss = v.x * v.x + v.y * v.y;
#pragma unroll
  for (int m = 1; m <= 32; m <<= 1) ss += __shfl_xor(ss, m, 64);
  float s = SQRT_LOG2E / sqrtf(ss);
  float2 sv;
  sv.x = v.x * s;
  sv.y = v.y * s;
  __hip_bfloat162 b2 = __float22bfloat162_rn(sv);
  // kc = (2*lane)>>3 = lane>>2 ; byte-in-cell = ((2*lane)&7)*2 = (lane&3)*4
  char* dst = catT + (size_t)(lane >> 2) * KCSTR + (size_t)row * 16 + (lane & 3) * 4;
  *(__hip_bfloat162*)dst = b2;
}

// Kernel 2: fused GEMM + exp2 + row-sum. NO LDS, NO barriers, NO asm.
// Each wave: 64 f-rows (A in regs), streams 512 cat-cols in 32-col chunks of
// direct coalesced global loads (kc-major layout). Waves fully decoupled —
// latency hidden by TLP + compiler scheduling. The 4 row-waves of a block
// read identical B addresses ~in phase -> L1 dedups the L2 traffic.
__global__ __launch_bounds__(256) void infonce_main(
    const char* __restrict__ catT,
    float* __restrict__ ws_neg, float* __restrict__ ws_pos) {
  const int tid = threadIdx.x;
  const int lane = tid & 63;
  const int w = tid >> 6;
  const int l15 = lane & 15, l4 = lane >> 4;
  const int nb = blockIdx.x, mb = blockIdx.y;
  const int growbase = mb * BM + w * 64;
  const int col0 = nb * COLS_PER_BLOCK;

  // per-lane base inside a kc-plane group: plane l4, col-offset l15
  const char* kbase = catT + (size_t)l4 * KCSTR + (size_t)l15 * 16;

  // A fragments: 64 f-rows (catT cols BS+grow), all of K=128 (64 VGPRs).
  bf16x8 a[4][4];
#pragma unroll
  for (int rf = 0; rf < 4; rf++)
#pragma unroll
    for (int kk = 0; kk < 4; kk++)
      a[rf][kk] = *(const bf16x8*)(kbase + (size_t)kk * (4 * KCSTR) +
                                   (size_t)(BS + growbase + rf * 16) * 16);

  float rowsum[16];
#pragma unroll
  for (int i = 0; i < 16; i++) rowsum[i] = 0.f;

  const char* bptr = kbase + (size_t)col0 * 16;

  for (int ch = 0; ch < NCHUNK; ++ch) {
    const char* bc = bptr + ch * (32 * 16);
    bf16x8 b[4][2];
#pragma unroll
    for (int kk = 0; kk < 4; kk++) {
      b[kk][0] = *(const bf16x8*)(bc + (size_t)kk * (4 * KCSTR));
      b[kk][1] = *(const bf16x8*)(bc + (size_t)kk * (4 * KCSTR) + 256);
    }

    f32x4 acc[4][2];
    const f32x4 z = {0.f, 0.f, 0.f, 0.f};
#pragma unroll
    for (int rf = 0; rf < 4; rf++) {
      acc[rf][0] = z;
      acc[rf][1] = z;
    }
#pragma unroll
    for (int kk = 0; kk < 4; kk++)
#pragma unroll
      for (int rf = 0; rf < 4; rf++) {
        acc[rf][0] = __builtin_amdgcn_mfma_f32_16x16x32_bf16(a[rf][kk], b[kk][0], acc[rf][0], 0, 0, 0);
        acc[rf][1] = __builtin_amdgcn_mfma_f32_16x16x32_bf16(a[rf][kk], b[kk][1], acc[rf][1], 0, 0, 0);
      }

    // epilogue: acc = sim*log2e -> exp2, accumulate row sums, excise diagonals.
    const int c0 = col0 + ch * 32;
    const bool dPos = ((c0 & ~63) == growbase);          // cols == f-row ids
    const bool dSelf = (((c0 - BS) & ~63) == growbase);  // cols == i+bs
    if (!dPos && !dSelf) {
#pragma unroll
      for (int rf = 0; rf < 4; rf++)
#pragma unroll
        for (int cf = 0; cf < 2; cf++)
#pragma unroll
          for (int r = 0; r < 4; r++) rowsum[rf * 4 + r] += EXP2F(acc[rf][cf][r]);
    } else {
#pragma unroll
      for (int rf = 0; rf < 4; rf++)
#pragma unroll
        for (int cf = 0; cf < 2; cf++)
#pragma unroll
          for (int r = 0; r < 4; r++) {
            const int grow = growbase + rf * 16 + l4 * 4 + r;
            const int gcol = c0 + cf * 16 + l15;
            const float v = acc[rf][cf][r];
            const bool ex = dPos ? (gcol == grow) : (gcol == grow + BS);
            if (dPos && gcol == grow) ws_pos[grow] = v;  // sim_pos * log2e
            rowsum[rf * 4 + r] += ex ? 0.f : EXP2F(v);
          }
    }
  }

  // reduce across the 16 lanes (l15) sharing each row
#pragma unroll
  for (int s = 0; s < 16; s++) {
    float v = rowsum[s];
    v += __shfl_xor(v, 1, 64);
    v += __shfl_xor(v, 2, 64);
    v += __shfl_xor(v, 4, 64);
    v += __shfl_xor(v, 8, 64);
    rowsum[s] = v;
  }
  if (l15 == 0) {
    float* dst = ws_neg + (size_t)nb * BS + growbase;
#pragma unroll
    for (int rf = 0; rf < 4; rf++)
#pragma unroll
      for (int r = 0; r < 4; r++) dst[rf * 16 + l4 * 4 + r] = rowsum[rf * 4 + r];
  }
}

// Kernel 3a: per-row loss, 32-block partial sums.
__global__ __launch_bounds__(256) void finalize1(const float* __restrict__ ws_neg,
                                                 const float* __restrict__ ws_pos,
                                                 float* __restrict__ partial) {
  const int row = blockIdx.x * 256 + threadIdx.x;
  float neg = 0.f;
#pragma unroll
  for (int p = 0; p < NPART; p++) neg += ws_neg[(size_t)p * BS + row];
  // loss = log(neg_sum + eps) - sim_pos ; sim_pos = (sim*log2e)*ln2
  float local = logf(neg + 1e-6f) - ws_pos[row] * LN2F;
#pragma unroll
  for (int m = 1; m <= 32; m <<= 1) local += __shfl_xor(local, m, 64);
  __shared__ float red[4];
  if ((threadIdx.x & 63) == 0) red[threadIdx.x >> 6] = local;
  __syncthreads();
  if (threadIdx.x == 0) partial[blockIdx.x] = red[0] + red[1] + red[2] + red[3];
}

// Kernel 3b: final mean over the 32 block partials.
__global__ void finalize2(const float* __restrict__ partial, float* __restrict__ out) {
  float v = ((int)threadIdx.x < 32) ? partial[threadIdx.x] : 0.f;
#pragma unroll
  for (int m = 1; m <= 32; m <<= 1) v += __shfl_xor(v, m, 64);
  if (threadIdx.x == 0) out[0] = v * (1.f / BS);
}

extern "C" void kernel_launch(void* const* d_in, const int* in_sizes, int n_in,
                              void* d_out, int out_size, void* d_ws, size_t ws_size,
                              hipStream_t stream) {
  const float* f = (const float*)d_in[0];
  const float* noise = (const float*)d_in[1];
  char* ws = (char*)d_ws;
  char* catT = ws;                                            // 4 MiB (kc-major)
  float* ws_pos = (float*)(ws + (size_t)NROWS * D * 2);       // 32 KiB
  float* ws_neg = ws_pos + BS;                                // 1 MiB
  float* partial = ws_neg + (size_t)NPART * BS;               // 128 B

  nrm_cvt<<<NROWS / 4, 256, 0, stream>>>(f, noise, catT);
  dim3 grid(NSPLIT, BS / BM);                                 // 32 x 32 = 1024 blocks
  infonce_main<<<grid, 256, 0, stream>>>(catT, ws_neg, ws_pos);
  finalize1<<<BS / 256, 256, 0, stream>>>(ws_neg, ws_pos, partial);
  finalize2<<<1, 64, 0, stream>>>(partial, (float*)d_out);
}

// Round 8
// 50.821 us; speedup vs baseline: 1.1766x; 1.1766x over previous
//
#include <hip/hip_runtime.h>
#include <hip/hip_bf16.h>
#include <math.h>

#define BS 8192
#define D 128
#define NROWS 16384               // 2*BS
#define BM 256                    // rows per block = 4 waves x 64
#define COLS_PER_BLOCK 512
#define NCHUNK (COLS_PER_BLOCK / 16)      // 32 col-chunks of 16
#define NSPLIT (NROWS / COLS_PER_BLOCK)   // 32
#define NPART NSPLIT                      // 32 partial buffers

typedef __bf16 bf16x8 __attribute__((ext_vector_type(8)));
typedef float f32x4 __attribute__((ext_vector_type(4)));

#define SQRT_LOG2E 1.2011224087864498f
#define LN2F 0.6931471805599453f

#if __has_builtin(__builtin_amdgcn_exp2f)
#define EXP2F(x) __builtin_amdgcn_exp2f(x)
#else
#define EXP2F(x) exp2f(x)
#endif

// Layout of catT ("chunk-tiled kc-major"): byte addr of (row, k) =
//   (row>>4)*4096 + (k>>3)*256 + (row&15)*16 + (k&7)*2
// -> an MFMA B-frag wave-load (16 cols x one kc, lanes l4=kc-sub, l15=col) is
//    1 KiB CONTIGUOUS, and a chunk's 4 loads are at immediate offsets
//    {0,1024,2048,3072} from one per-lane base (13-bit folding, 1 add/chunk).

// Kernel 1: row norms + pre-scaled bf16 conversion into catT.
// Rows scaled by sqrt(log2e)/||row|| so MFMA yields cos_sim*log2e directly.
__global__ __launch_bounds__(256) void nrm_cvt(const float* __restrict__ f,
                                               const float* __restrict__ noise,
                                               char* __restrict__ catT) {
  const int lane = threadIdx.x & 63;
  const int wv = threadIdx.x >> 6;
  const int row = blockIdx.x * 4 + wv;
  const float* src = (row < BS) ? (noise + (size_t)row * D) : (f + (size_t)(row - BS) * D);
  float2 v = ((const float2*)src)[lane];   // k = 2*lane, 2*lane+1  (same kc cell)
  float ss = v.x * v.x + v.y * v.y;
#pragma unroll
  for (int m = 1; m <= 32; m <<= 1) ss += __shfl_xor(ss, m, 64);
  float s = SQRT_LOG2E / sqrtf(ss);
  float2 sv;
  sv.x = v.x * s;
  sv.y = v.y * s;
  __hip_bfloat162 b2 = __float22bfloat162_rn(sv);
  char* dst = catT + ((size_t)(row >> 4) << 12) + ((lane >> 2) << 8) +
              ((row & 15) << 4) + ((lane & 3) << 2);
  *(__hip_bfloat162*)dst = b2;
}

// Kernel 2: fused GEMM + exp2 + row-sum. No LDS, no barriers. Each wave owns
// 64 f-rows (A in regs) and streams 512 cat-cols in 16-col chunks with a
// REGISTER DOUBLE-BUFFER: loads for chunk t+1 issue before chunk t's MFMA+exp,
// giving ~270 issue-cycles of within-wave latency cover (x4 waves/SIMD).
__global__ __launch_bounds__(256) void infonce_main(
    const char* __restrict__ catT,
    float* __restrict__ ws_neg, float* __restrict__ ws_pos) {
  const int tid = threadIdx.x;
  const int lane = tid & 63;
  const int w = tid >> 6;
  const int l15 = lane & 15, l4 = lane >> 4;
  const int nb = blockIdx.x, mb = blockIdx.y;
  const int growbase = mb * BM + w * 64;
  const int col0 = nb * COLS_PER_BLOCK;

  // per-lane fragment base inside a chunk: kc-sub l4, col l15
  const int lbase = l4 * 256 + l15 * 16;

  // A fragments: 64 f-rows (catT rows BS+grow..), all of K=128 (64 VGPRs).
  bf16x8 a[4][4];
  {
    const char* ab = catT + (size_t)(BS + growbase) * 256 + lbase;
#pragma unroll
    for (int rf = 0; rf < 4; rf++)
#pragma unroll
      for (int kk = 0; kk < 4; kk++)
        a[rf][kk] = *(const bf16x8*)(ab + rf * 4096 + kk * 1024);
  }

  float rowsum[16];
#pragma unroll
  for (int i = 0; i < 16; i++) rowsum[i] = 0.f;

  const char* bl = catT + (size_t)col0 * 256 + lbase;

  auto loadB = [&](bf16x8* b, int ch) {
    const char* p = bl + (size_t)ch * 4096;
#pragma unroll
    for (int kk = 0; kk < 4; kk++) b[kk] = *(const bf16x8*)(p + kk * 1024);
  };

  bf16x8 bb[2][4];
  loadB(bb[0], 0);

  const f32x4 z = {0.f, 0.f, 0.f, 0.f};

#pragma unroll
  for (int ch = 0; ch < NCHUNK; ++ch) {
    const int cu = ch & 1;         // compile-time under full unroll
    if (ch + 1 < NCHUNK) loadB(bb[cu ^ 1], ch + 1);

    f32x4 acc[4];
#pragma unroll
    for (int rf = 0; rf < 4; rf++)
      acc[rf] = __builtin_amdgcn_mfma_f32_16x16x32_bf16(a[rf][0], bb[cu][0], z, 0, 0, 0);
#pragma unroll
    for (int kk = 1; kk < 4; kk++)
#pragma unroll
      for (int rf = 0; rf < 4; rf++)
        acc[rf] = __builtin_amdgcn_mfma_f32_16x16x32_bf16(a[rf][kk], bb[cu][kk], acc[rf], 0, 0, 0);

    // epilogue: acc = sim*log2e -> exp2, accumulate row sums, excise diagonals.
    const int c0 = col0 + ch * 16;
    const bool dPos = ((c0 & ~63) == growbase);          // cols == f-row ids
    const bool dSelf = (((c0 - BS) & ~63) == growbase);  // cols == i+bs
    if (!dPos && !dSelf) {
#pragma unroll
      for (int rf = 0; rf < 4; rf++)
#pragma unroll
        for (int r = 0; r < 4; r++) rowsum[rf * 4 + r] += EXP2F(acc[rf][r]);
    } else {
#pragma unroll
      for (int rf = 0; rf < 4; rf++)
#pragma unroll
        for (int r = 0; r < 4; r++) {
          const int grow = growbase + rf * 16 + l4 * 4 + r;
          const int gcol = c0 + l15;
          const float v = acc[rf][r];
          const bool ex = dPos ? (gcol == grow) : (gcol == grow + BS);
          if (dPos && gcol == grow) ws_pos[grow] = v;  // sim_pos * log2e
          rowsum[rf * 4 + r] += ex ? 0.f : EXP2F(v);
        }
    }
  }

  // reduce across the 16 lanes (l15) sharing each row
#pragma unroll
  for (int s = 0; s < 16; s++) {
    float v = rowsum[s];
    v += __shfl_xor(v, 1, 64);
    v += __shfl_xor(v, 2, 64);
    v += __shfl_xor(v, 4, 64);
    v += __shfl_xor(v, 8, 64);
    rowsum[s] = v;
  }
  if (l15 == 0) {
    float* dst = ws_neg + (size_t)nb * BS + growbase;
#pragma unroll
    for (int rf = 0; rf < 4; rf++)
#pragma unroll
      for (int r = 0; r < 4; r++) dst[rf * 16 + l4 * 4 + r] = rowsum[rf * 4 + r];
  }
}

// Kernel 3a: per-row loss, 32-block partial sums.
__global__ __launch_bounds__(256) void finalize1(const float* __restrict__ ws_neg,
                                                 const float* __restrict__ ws_pos,
                                                 float* __restrict__ partial) {
  const int row = blockIdx.x * 256 + threadIdx.x;
  float neg = 0.f;
#pragma unroll
  for (int p = 0; p < NPART; p++) neg += ws_neg[(size_t)p * BS + row];
  // loss = log(neg_sum + eps) - sim_pos ; sim_pos = (sim*log2e)*ln2
  float local = logf(neg + 1e-6f) - ws_pos[row] * LN2F;
#pragma unroll
  for (int m = 1; m <= 32; m <<= 1) local += __shfl_xor(local, m, 64);
  __shared__ float red[4];
  if ((threadIdx.x & 63) == 0) red[threadIdx.x >> 6] = local;
  __syncthreads();
  if (threadIdx.x == 0) partial[blockIdx.x] = red[0] + red[1] + red[2] + red[3];
}

// Kernel 3b: final mean over the 32 block partials.
__global__ void finalize2(const float* __restrict__ partial, float* __restrict__ out) {
  float v = ((int)threadIdx.x < 32) ? partial[threadIdx.x] : 0.f;
#pragma unroll
  for (int m = 1; m <= 32; m <<= 1) v += __shfl_xor(v, m, 64);
  if (threadIdx.x == 0) out[0] = v * (1.f / BS);
}

extern "C" void kernel_launch(void* const* d_in, const int* in_sizes, int n_in,
                              void* d_out, int out_size, void* d_ws, size_t ws_size,
                              hipStream_t stream) {
  const float* f = (const float*)d_in[0];
  const float* noise = (const float*)d_in[1];
  char* ws = (char*)d_ws;
  char* catT = ws;                                            // 4 MiB (chunk-tiled)
  float* ws_pos = (float*)(ws + (size_t)NROWS * D * 2);       // 32 KiB
  float* ws_neg = ws_pos + BS;                                // 1 MiB
  float* partial = ws_neg + (size_t)NPART * BS;               // 128 B

  nrm_cvt<<<NROWS / 4, 256, 0, stream>>>(f, noise, catT);
  dim3 grid(NSPLIT, BS / BM);                                 // 32 x 32 = 1024 blocks
  infonce_main<<<grid, 256, 0, stream>>>(catT, ws_neg, ws_pos);
  finalize1<<<BS / 256, 256, 0, stream>>>(ws_neg, ws_pos, partial);
  finalize2<<<1, 64, 0, stream>>>(partial, (float*)d_out);
}